// Round 8
// baseline (190.842 us; speedup 1.0000x reference)
//
#include <hip/hip_runtime.h>

// ---------------------------------------------------------------------------
// MultiheadSelfAttention (row-local head-mixing variant), MI355X / gfx950.
// Round 16: asymmetric swizzle consolidation.  R15 proved GEMM1 is NOT
// supply-bound (FETCH -36% with time +1.7us): XCD-chunking thrashes its L2
// (A 2MB + B 6MB > 4MB) -> revert GEMM1 to the 2D grid (R14: 59.7us).
// GEMM2 keeps the XCD chunk (working set 2MB Wproj + 2MB A = fits L2; R15
// measured win).  All kernels otherwise identical to R14/R15 proven state.
// ---------------------------------------------------------------------------

typedef __bf16 bf16x8 __attribute__((ext_vector_type(8)));
typedef float  f32x16 __attribute__((ext_vector_type(16)));

typedef __attribute__((address_space(3))) void       lds_void;
typedef const __attribute__((address_space(1))) void gbl_void;

__device__ __forceinline__ unsigned short f2b(float f) {
    unsigned int u = __builtin_bit_cast(unsigned int, f);
    return (unsigned short)((u + 0x7FFFu + ((u >> 16) & 1u)) >> 16);  // RNE
}
__device__ __forceinline__ unsigned int pack2(float a, float b) {
    return (unsigned int)f2b(a) | ((unsigned int)f2b(b) << 16);
}
__device__ __forceinline__ void unpack8(uint4 u, float* f) {
    unsigned int w[4] = {u.x, u.y, u.z, u.w};
#pragma unroll
    for (int a = 0; a < 4; ++a) {
        union { unsigned int i; float f; } lo, hi;
        lo.i = w[a] << 16;
        hi.i = w[a] & 0xFFFF0000u;
        f[a * 2]     = lo.f;
        f[a * 2 + 1] = hi.f;
    }
}

// ------------------------- fused fp32 -> bf16 cast -------------------------
__global__ __launch_bounds__(256) void cvt_all(const float* __restrict__ x,
                                               const float* __restrict__ wqkv,
                                               const float* __restrict__ wproj,
                                               unsigned short* __restrict__ xb,
                                               unsigned short* __restrict__ wqkvb,
                                               unsigned short* __restrict__ wprojb) {
    int i = blockIdx.x * 256 + threadIdx.x;
    const float* src;
    unsigned short* dst;
    if (i < 2097152)      { src = x;     dst = xb;                   }
    else if (i < 2883584) { src = wqkv;  dst = wqkvb;  i -= 2097152; }
    else                  { src = wproj; dst = wprojb; i -= 2883584; }
    float4 f = reinterpret_cast<const float4*>(src)[i];
    ushort4 u;
    u.x = f2b(f.x); u.y = f2b(f.y); u.z = f2b(f.z); u.w = f2b(f.w);
    reinterpret_cast<ushort4*>(dst)[i] = u;
}

// --------------------------- bf16 NT GEMM ----------------------------------
// C[m,n] = sum_k A[m,k]*B[n,k].  A: MxK rm, B: NxK rm (bf16 bits as ushort).
// Block tile BMxBN, BK=64.  4 waves 2x2; wave tile (BM/2)x(BN/2) as MIxNJ
// tiles of 32x32x16 MFMA.  LDS rows = 8 chunks of 16B; chunk c of row r at
// slot c^(r&7) -> conflict-free staging, swizzled reads.
// SWZ=false: 2D grid, bm=blockIdx.y, bn=blockIdx.x (GEMM1 -- L2 chunking
// thrashes its 8MB working set, proven R15).  SWZ=true: 1-D grid with
// XCD-chunked bijective remap (GEMM2 -- 4MB working set fits L2, proven win).
__device__ __forceinline__ void store_c(float* C, long idx, float v)          { C[idx] = v; }
__device__ __forceinline__ void store_c(unsigned short* C, long idx, float v) { C[idx] = f2b(v); }

template <int BM, int BN, bool SWZ, typename CT>
__global__ __launch_bounds__(256, 3) void gemm_bt(const unsigned short* __restrict__ A,
                                                  const unsigned short* __restrict__ B,
                                                  CT* __restrict__ C,
                                                  int M, int N, int K, int NBX) {
    constexpr int MI = BM / 64;                    // 32-row MFMA tiles per wave (M)
    constexpr int NJ = BN / 64;                    // 32-col MFMA tiles per wave (N)
    __shared__ __align__(16) unsigned short As[BM * 64];
    __shared__ __align__(16) unsigned short Bs[BN * 64];

    const int tid  = threadIdx.x;
    const int lane = tid & 63;
    const int wave = tid >> 6;

    long bm, bn;
    if constexpr (SWZ) {
        // XCD-chunked bijective swizzle (gridDim.x % 8 == 0)
        const int wg   = blockIdx.x;
        const int cpx  = (int)gridDim.x >> 3;      // tiles per XCD chunk
        const int tile = (wg & 7) * cpx + (wg >> 3);
        bm = tile / NBX;
        bn = tile % NBX;
    } else {
        bm = blockIdx.y;
        bn = blockIdx.x;
    }

    const int wm   = (wave >> 1) * (BM / 2);
    const int wn   = (wave & 1) * (BN / 2);

    f32x16 acc[MI][NJ] = {};

    const unsigned short* Ab = A + bm * BM * (long)K;
    const unsigned short* Bb = B + bn * BN * (long)K;

    const int srow  = tid >> 3;                        // row within 32-row group
    const int sgcol = ((tid & 7) ^ (srow & 7)) << 3;   // swizzled SOURCE chunk

    for (int k0 = 0; k0 < K; k0 += 64) {
#pragma unroll
        for (int r = 0; r < BM / 32; ++r)
            __builtin_amdgcn_global_load_lds(
                (gbl_void*)(Ab + (long)(r * 32 + srow) * K + k0 + sgcol),
                (lds_void*)(As + (r * 256 + wave * 64) * 8), 16, 0, 0);
#pragma unroll
        for (int r = 0; r < BN / 32; ++r)
            __builtin_amdgcn_global_load_lds(
                (gbl_void*)(Bb + (long)(r * 32 + srow) * K + k0 + sgcol),
                (lds_void*)(Bs + (r * 256 + wave * 64) * 8), 16, 0, 0);
        __syncthreads();

        const int arow = lane & 31;
        const int kh   = lane >> 5;                    // k-half: k = kh*8 + j
#pragma unroll
        for (int kk = 0; kk < 4; ++kk) {               // 4 x K=16
            const int c  = kk * 2 + kh;                // logical chunk 0..7
            const int sw = (c ^ (lane & 7)) << 3;      // swizzled read offset
            bf16x8 af[MI], bfr[NJ];
#pragma unroll
            for (int i = 0; i < MI; ++i)
                af[i] = *reinterpret_cast<const bf16x8*>(As + (wm + i * 32 + arow) * 64 + sw);
#pragma unroll
            for (int j = 0; j < NJ; ++j)
                bfr[j] = *reinterpret_cast<const bf16x8*>(Bs + (wn + j * 32 + arow) * 64 + sw);
#pragma unroll
            for (int i = 0; i < MI; ++i)
#pragma unroll
                for (int j = 0; j < NJ; ++j)
                    acc[i][j] = __builtin_amdgcn_mfma_f32_32x32x16_bf16(af[i], bfr[j], acc[i][j], 0, 0, 0);
        }
        __syncthreads();
    }

    // C/D layout (verified m74/m101): col=lane&31, row=(r&3)+8*(r>>2)+4*(lane>>5)
    const long mbase = bm * BM + wm + ((lane >> 5) << 2);
    const long nbase = bn * BN + wn + (lane & 31);
#pragma unroll
    for (int i = 0; i < MI; ++i)
#pragma unroll
        for (int j = 0; j < NJ; ++j)
#pragma unroll
            for (int r = 0; r < 16; ++r) {
                const long row = mbase + i * 32 + (r & 3) + 8 * (r >> 2);
                store_c(C, row * (long)N + nbase + j * 32, acc[i][j][r]);
            }
}

// ------------------- per-row head attention + scatter ----------------------
// qkv row m=(b,t): q=e[0,1024), k=e[1024,2048), v=e[2048,3072); h=e/64%16.
// scores[i][j]=0.125*dot64(q_i,k_j); softmax over j; out[i][s]=sum_j a*v.
// Scatter: out[b,t,h,s] -> out3[b, h*128 + t/16, 64*(t%16)+s].
// rows[] is XOR chunk-swizzled: chunk c of 64-elem vector vi at c^(vi&7).
__global__ __launch_bounds__(256) void attn_rowlocal(const unsigned short* __restrict__ qkv,
                                                     unsigned short* __restrict__ out3) {
    __shared__ __align__(16) unsigned short rows[4 * 3072];  // 24 KB, swizzled
    __shared__ float attnS[4][16][17];                       // padded

    const int tid  = threadIdx.x;
    const int lane = tid & 63;
    const int wave = tid >> 6;
    const int m0   = blockIdx.x * 4;

    {   // cooperative load: LDS slot S gets global chunk (S&~7)|((S&7)^((S>>3)&7))
        const uint4* src = reinterpret_cast<const uint4*>(qkv + (long)m0 * 3072);
        uint4* dst = reinterpret_cast<uint4*>(rows);
#pragma unroll
        for (int c = 0; c < 6; ++c) {
            const int S  = c * 256 + tid;
            const int gs = (S & ~7) | ((S & 7) ^ ((S >> 3) & 7));
            dst[S] = src[gs];
        }
    }
    __syncthreads();

    const int m = m0 + wave;
    const int b = m >> 11;
    const int t = m & 2047;
    const unsigned short* rw = rows + wave * 3072;

    // scores: lane handles i = lane&15, j in [(lane>>4)*4, +4)
    const int i  = lane & 15;
    const int j0 = (lane >> 4) << 2;
    float sc[4] = {0.f, 0.f, 0.f, 0.f};
#pragma unroll
    for (int c8 = 0; c8 < 8; ++c8) {
        uint4 qu = *reinterpret_cast<const uint4*>(rw + i * 64 + ((c8 ^ (i & 7)) << 3));
        float qf[8];
        unpack8(qu, qf);
#pragma unroll
        for (int jj = 0; jj < 4; ++jj) {
            const int vi = 16 + j0 + jj;
            uint4 ku = *reinterpret_cast<const uint4*>(rw + vi * 64 + ((c8 ^ (vi & 7)) << 3));
            float kf[8];
            unpack8(ku, kf);
#pragma unroll
            for (int d = 0; d < 8; ++d) sc[jj] += qf[d] * kf[d];
        }
    }
#pragma unroll
    for (int jj = 0; jj < 4; ++jj) sc[jj] *= 0.125f;

    float mx = fmaxf(fmaxf(sc[0], sc[1]), fmaxf(sc[2], sc[3]));
    mx = fmaxf(mx, __shfl_xor(mx, 16));
    mx = fmaxf(mx, __shfl_xor(mx, 32));
    float sum = 0.f;
#pragma unroll
    for (int jj = 0; jj < 4; ++jj) { sc[jj] = __expf(sc[jj] - mx); sum += sc[jj]; }
    sum += __shfl_xor(sum, 16);
    sum += __shfl_xor(sum, 32);
    const float inv = 1.0f / sum;
#pragma unroll
    for (int jj = 0; jj < 4; ++jj) attnS[wave][i][j0 + jj] = sc[jj] * inv;
    __syncthreads();

    // out: lane handles head oi = lane>>2, s chunk s0 = (lane&3)*16
    const int oi = lane >> 2;
    const int s0 = (lane & 3) << 4;
    const int c0 = (lane & 3) << 1;
    float o[16];
#pragma unroll
    for (int ss = 0; ss < 16; ++ss) o[ss] = 0.f;
#pragma unroll
    for (int j = 0; j < 16; ++j) {
        const float a  = attnS[wave][oi][j];
        const int   vi = 32 + j;
        uint4 v0 = *reinterpret_cast<const uint4*>(rw + vi * 64 + (((c0)     ^ (vi & 7)) << 3));
        uint4 v1 = *reinterpret_cast<const uint4*>(rw + vi * 64 + (((c0 + 1) ^ (vi & 7)) << 3));
        float vf[16];
        unpack8(v0, vf);
        unpack8(v1, vf + 8);
#pragma unroll
        for (int ss = 0; ss < 16; ++ss) o[ss] += a * vf[ss];
    }

    uint4 r0, r1;
    r0.x = pack2(o[0],  o[1]);  r0.y = pack2(o[2],  o[3]);
    r0.z = pack2(o[4],  o[5]);  r0.w = pack2(o[6],  o[7]);
    r1.x = pack2(o[8],  o[9]);  r1.y = pack2(o[10], o[11]);
    r1.z = pack2(o[12], o[13]); r1.w = pack2(o[14], o[15]);

    const long base = (long)b * (2048 * 1024)
                    + (long)(oi * 128 + (t >> 4)) * 1024
                    + 64 * (t & 15) + s0;
    *reinterpret_cast<uint4*>(out3 + base)     = r0;
    *reinterpret_cast<uint4*>(out3 + base + 8) = r1;
}

// ------------------------------- launcher ----------------------------------
extern "C" void kernel_launch(void* const* d_in, const int* in_sizes, int n_in,
                              void* d_out, int out_size, void* d_ws, size_t ws_size,
                              hipStream_t stream) {
    const float* x     = (const float*)d_in[0];   // (4,2048,1024)
    const float* Wqkv  = (const float*)d_in[1];   // (3072,1024)
    const float* Wproj = (const float*)d_in[2];   // (1024,1024)
    float* out = (float*)d_out;                   // (4,2048,1024) fp32

    char* ws = (char*)d_ws;
    unsigned short* xb     = (unsigned short*)(ws);               // 16.0 MiB
    unsigned short* wqkvb  = (unsigned short*)(ws + 16777216);    //  6.0 MiB
    unsigned short* wprojb = (unsigned short*)(ws + 23068672);    //  2.0 MiB
    unsigned short* qkvb   = (unsigned short*)(ws + 25165824);    // 48.0 MiB
    unsigned short* out3b  = (unsigned short*)(ws + 75497472);    // 16.0 MiB

    // all three fp32->bf16 casts in one dispatch (3,145,728 float4s)
    cvt_all<<<dim3(12288), dim3(256), 0, stream>>>(x, Wqkv, Wproj, xb, wqkvb, wprojb);

    // qkv = x @ Wqkv^T : M=8192, N=3072, K=1024
    // 128x256 tiles, 2D grid (R14 mapping, 59.7us; XCD chunk thrashes -> off)
    gemm_bt<128, 256, false, unsigned short><<<dim3(12, 64), dim3(256), 0, stream>>>(
        xb, wqkvb, qkvb, 8192, 3072, 1024, 12);

    attn_rowlocal<<<dim3(2048), dim3(256), 0, stream>>>(qkvb, out3b);

    // out = out3 @ Wproj^T : M=8192, N=1024, K=1024
    // 128x128 tiles, 512 blocks, XCD-chunked (working set fits L2 -> proven win)
    gemm_bt<128, 128, true, float><<<dim3(512), dim3(256), 0, stream>>>(
        out3b, wprojb, out, 8192, 1024, 1024, 8);
}